// Round 1
// baseline (742.815 us; speedup 1.0000x reference)
//
#include <hip/hip_runtime.h>

// ---------------------------------------------------------------------------
// QoSNet: gather -> 32-step GRU(D=128) -> batchnorm -> 3x SELU MLP readout
// BS=8192, N_LINKS=512, MAX_LEN=32, D_LINK=32 (only last 4 dims nonzero),
// D_PATH=128, D_READ=256, N_OUT=3.  All f32.
// f32-VALU-bound on the GRU recurrence (12.9 GMAC); no fp32 MFMA on CDNA4.
// ---------------------------------------------------------------------------

#define BS 8192
#define NL 512
#define ML 32
#define DP 128
#define DR 256

// workspace layout (float offsets)
#define OFF_SUM 64
#define OFF_SSQ 192
#define OFF_A   320
#define OFF_B   448
#define OFF_WT  576                    // 384*128 = 49152 floats (W_hh relaid out)
#define OFF_FEATS (OFF_WT + 49152)     // BS*ML*4 = 1048576 floats
#define OFF_FLOW  (OFF_FEATS + BS*ML*4) // BS*128 = 1048576 floats
// total ~8.2 MiB of d_ws

__device__ __forceinline__ float sigmoidf_(float x){ return 1.0f/(1.0f+__expf(-x)); }
__device__ __forceinline__ float tanhf_(float x){
  float t = __expf(-2.0f*fabsf(x));
  float r = (1.0f-t)/(1.0f+t);
  return copysignf(r, x);
}
__device__ __forceinline__ float seluf_(float x){
  const float sc = 1.0507009873554805f, al = 1.6732632423543772f;
  return x > 0.0f ? sc*x : sc*al*(__expf(x)-1.0f);
}

__global__ void kzero(float* ws){
  for (int i = threadIdx.x; i < 576; i += 256) ws[i] = 0.0f;
}

__global__ void kmax(const float* __restrict__ capa, float* ws){
  const float4* c4 = (const float4*)capa;
  const int n4 = BS*NL/4;
  float m = 0.0f;
  for (int i = blockIdx.x*blockDim.x + threadIdx.x; i < n4; i += gridDim.x*blockDim.x){
    float4 v = c4[i];
    m = fmaxf(m, fmaxf(fmaxf(v.x, v.y), fmaxf(v.z, v.w)));
  }
  #pragma unroll
  for (int o = 32; o > 0; o >>= 1) m = fmaxf(m, __shfl_down(m, o, 64));
  if ((threadIdx.x & 63) == 0) atomicMax((int*)ws, __float_as_int(m)); // vals > 0
}

// relayout W_hh[row][k] (384x128) -> wt[k4][row][c] so GRU loads are coalesced
__global__ void ktrans(const float* __restrict__ whh, float* __restrict__ wt){
  int o = blockIdx.x*256 + threadIdx.x;
  if (o >= 384*128) return;
  int c  = o & 3;
  int r2 = o >> 2;
  int row = r2 % 384;
  int k4  = r2 / 384;
  wt[o] = whh[row*128 + k4*4 + c];
}

__global__ void kfeats(const int* __restrict__ path, const int* __restrict__ hop,
                       const float* __restrict__ avail, const float* __restrict__ capa,
                       const float* __restrict__ loss, const float* __restrict__ ws,
                       float* __restrict__ feats){
  int idx = blockIdx.x*256 + threadIdx.x;   // over BS*ML
  if (idx >= BS*ML) return;
  int b = idx >> 5, t = idx & 31;
  float4 f = make_float4(0.f, 0.f, 0.f, 0.f);
  if (t < hop[b]){
    int l = path[idx];
    float maxc = ws[0];
    float a = avail[b*NL + l];
    float c = capa [b*NL + l];
    f.x = a / maxc; f.y = c / maxc; f.z = a / c; f.w = loss[b*NL + l];
  }
  ((float4*)feats)[idx] = f;
}

// GRU: block = 2 halves x 128 channels; 16 items/block (8 per half).
// thread j owns channel j of its 8 items; h lives in LDS (broadcast reads).
__launch_bounds__(256, 2)
__global__ void kgru(const float* __restrict__ feats, const float* __restrict__ demand,
                     const int* __restrict__ hop, const float* __restrict__ wt,
                     const float* __restrict__ wih, const float* __restrict__ bih,
                     const float* __restrict__ bhh, const float* __restrict__ ws,
                     float* __restrict__ flow){
  __shared__ float h_lds[16][DP];
  __shared__ float f_lds[16][4];
  const int tid  = threadIdx.x;
  const int j    = tid & 127;
  const int half = tid >> 7;
  const int b0   = blockIdx.x * 16;
  const float maxc = ws[0];

  float wr[4], wz[4], wn[4];
  #pragma unroll
  for (int c = 0; c < 4; ++c){
    wr[c] = wih[(j      )*32 + 28 + c];
    wz[c] = wih[(j + 128)*32 + 28 + c];
    wn[c] = wih[(j + 256)*32 + 28 + c];
  }
  const float br   = bih[j]       + bhh[j];
  const float bz   = bih[j + 128] + bhh[j + 128];
  const float bn_i = bih[j + 256];
  const float bn_h = bhh[j + 256];

  int   hops[8];
  float hcur[8];
  #pragma unroll
  for (int i = 0; i < 8; ++i){
    int b = b0 + half*8 + i;
    hops[i] = hop[b];
    float h0 = (j == 127) ? demand[b]/maxc : 0.0f;
    hcur[i] = h0;
    h_lds[half*8 + i][j] = h0;
  }
  __syncthreads();

  for (int t = 0; t < ML; ++t){
    if (tid < 64){
      int i = tid >> 2, c = tid & 3;
      f_lds[i][c] = feats[(b0 + i)*(ML*4) + t*4 + c];
    }
    __syncthreads();

    float ar[8], az[8], an[8];
    #pragma unroll
    for (int i = 0; i < 8; ++i){ ar[i] = 0.f; az[i] = 0.f; an[i] = 0.f; }

    for (int k4 = 0; k4 < 32; ++k4){
      const float4 w_r = *(const float4*)(wt + (k4*384 + j      )*4);
      const float4 w_z = *(const float4*)(wt + (k4*384 + j + 128)*4);
      const float4 w_n = *(const float4*)(wt + (k4*384 + j + 256)*4);
      #pragma unroll
      for (int i = 0; i < 8; ++i){
        const float4 hv = *(const float4*)(&h_lds[half*8 + i][k4*4]); // wave-uniform -> LDS broadcast
        ar[i] = fmaf(w_r.x, hv.x, fmaf(w_r.y, hv.y, fmaf(w_r.z, hv.z, fmaf(w_r.w, hv.w, ar[i]))));
        az[i] = fmaf(w_z.x, hv.x, fmaf(w_z.y, hv.y, fmaf(w_z.z, hv.z, fmaf(w_z.w, hv.w, az[i]))));
        an[i] = fmaf(w_n.x, hv.x, fmaf(w_n.y, hv.y, fmaf(w_n.z, hv.z, fmaf(w_n.w, hv.w, an[i]))));
      }
    }

    #pragma unroll
    for (int i = 0; i < 8; ++i){
      if (t < hops[i]){   // uniform across the half-group (same items)
        int ii = half*8 + i;
        float f0 = f_lds[ii][0], f1 = f_lds[ii][1], f2 = f_lds[ii][2], f3 = f_lds[ii][3];
        float gr = fmaf(wr[0], f0, fmaf(wr[1], f1, fmaf(wr[2], f2, wr[3]*f3)));
        float gz = fmaf(wz[0], f0, fmaf(wz[1], f1, fmaf(wz[2], f2, wz[3]*f3)));
        float gn = fmaf(wn[0], f0, fmaf(wn[1], f1, fmaf(wn[2], f2, wn[3]*f3)));
        float r = sigmoidf_(ar[i] + br + gr);
        float z = sigmoidf_(az[i] + bz + gz);
        float n = tanhf_(gn + bn_i + r*(an[i] + bn_h));
        hcur[i] = fmaf(z, hcur[i] - n, n);   // (1-z)*n + z*h
      }
    }
    __syncthreads();
    #pragma unroll
    for (int i = 0; i < 8; ++i) h_lds[half*8 + i][j] = hcur[i];
    __syncthreads();
  }

  #pragma unroll
  for (int i = 0; i < 8; ++i) flow[(b0 + half*8 + i)*DP + j] = hcur[i];
}

__global__ void kstats(const float* __restrict__ flow, float* ws){
  int j = threadIdx.x & 127;
  int g = threadIdx.x >> 7;
  float s = 0.f, q = 0.f;
  for (int ii = 0; ii < 32; ++ii){
    int b = blockIdx.x*64 + g*32 + ii;
    float v = flow[b*DP + j];
    s += v; q = fmaf(v, v, q);
  }
  atomicAdd(&ws[OFF_SUM + j], s);
  atomicAdd(&ws[OFF_SSQ + j], q);
}

__global__ void kfinal(float* ws, const float* __restrict__ gamma, const float* __restrict__ beta){
  int j = threadIdx.x;
  float m = ws[OFF_SUM + j] * (1.0f/BS);
  float q = ws[OFF_SSQ + j] * (1.0f/BS);
  float rstd = rsqrtf(q - m*m + 1e-5f);
  float a = rstd * gamma[j];
  ws[OFF_A + j] = a;
  ws[OFF_B + j] = fmaf(-m, a, beta[j]);
}

// BN + 3-headed MLP readout. 16 items/block, 256 threads (thread = out neuron).
__launch_bounds__(256, 2)
__global__ void kmlp(const float* __restrict__ flow, const float* __restrict__ ws,
                     const float* __restrict__ rW1, const float* __restrict__ rb1,
                     const float* __restrict__ rW2, const float* __restrict__ rb2,
                     const float* __restrict__ rW3, const float* __restrict__ rb3,
                     float* __restrict__ out){
  __shared__ float nf[16][DP];
  __shared__ float h1[16][DR];
  __shared__ float red[16][4];
  const int tid = threadIdx.x;
  const int b0  = blockIdx.x * 16;

  for (int idx = tid; idx < 16*DP; idx += 256){
    int i = idx >> 7, h = idx & 127;
    nf[i][h] = fmaf(flow[(b0 + i)*DP + h], ws[OFF_A + h], ws[OFF_B + h]);
  }
  __syncthreads();

  for (int u = 0; u < 3; ++u){
    float acc[16];
    float b1 = rb1[u*DR + tid];
    #pragma unroll
    for (int i = 0; i < 16; ++i) acc[i] = b1;
    for (int h = 0; h < DP; ++h){
      float w = rW1[(u*DP + h)*DR + tid];        // coalesced
      #pragma unroll
      for (int i = 0; i < 16; ++i) acc[i] = fmaf(nf[i][h], w, acc[i]);
    }
    #pragma unroll
    for (int i = 0; i < 16; ++i) h1[i][tid] = seluf_(acc[i]);
    __syncthreads();

    float acc2[16];
    float b2 = rb2[u*DR + tid];
    #pragma unroll
    for (int i = 0; i < 16; ++i) acc2[i] = b2;
    for (int r = 0; r < DR; ++r){
      float w = rW2[(u*DR + r)*DR + tid];        // coalesced
      #pragma unroll
      for (int i = 0; i < 16; ++i) acc2[i] = fmaf(h1[i][r], w, acc2[i]);
    }
    float w3 = rW3[u*DR + tid];
    float val[16];
    #pragma unroll
    for (int i = 0; i < 16; ++i) val[i] = seluf_(acc2[i]) * w3;
    #pragma unroll
    for (int o = 32; o > 0; o >>= 1){
      #pragma unroll
      for (int i = 0; i < 16; ++i) val[i] += __shfl_down(val[i], o, 64);
    }
    if ((tid & 63) == 0){
      int w = tid >> 6;
      #pragma unroll
      for (int i = 0; i < 16; ++i) red[i][w] = val[i];
    }
    __syncthreads();
    if (tid < 16){
      float y = red[tid][0] + red[tid][1] + red[tid][2] + red[tid][3] + rb3[u];
      out[(b0 + tid)*3 + u] = y;
    }
    __syncthreads();   // h1 reused next u
  }
}

extern "C" void kernel_launch(void* const* d_in, const int* in_sizes, int n_in,
                              void* d_out, int out_size, void* d_ws, size_t ws_size,
                              hipStream_t stream){
  const float* demand = (const float*)d_in[0];
  const float* avail  = (const float*)d_in[1];
  const float* capa   = (const float*)d_in[2];
  const float* loss   = (const float*)d_in[3];
  const int*   path   = (const int*)d_in[4];
  const int*   hop    = (const int*)d_in[5];
  const float* wih    = (const float*)d_in[6];
  const float* whh    = (const float*)d_in[7];
  const float* bih    = (const float*)d_in[8];
  const float* bhh    = (const float*)d_in[9];
  const float* gamma  = (const float*)d_in[10];
  const float* beta   = (const float*)d_in[11];
  const float* rW1    = (const float*)d_in[12];
  const float* rb1    = (const float*)d_in[13];
  const float* rW2    = (const float*)d_in[14];
  const float* rb2    = (const float*)d_in[15];
  const float* rW3    = (const float*)d_in[16];
  const float* rb3    = (const float*)d_in[17];
  float* ws  = (float*)d_ws;
  float* out = (float*)d_out;

  kzero  <<<1, 256, 0, stream>>>(ws);
  kmax   <<<1024, 256, 0, stream>>>(capa, ws);
  ktrans <<<(384*128 + 255)/256, 256, 0, stream>>>(whh, ws + OFF_WT);
  kfeats <<<BS*ML/256, 256, 0, stream>>>(path, hop, avail, capa, loss, ws, ws + OFF_FEATS);
  kgru   <<<BS/16, 256, 0, stream>>>(ws + OFF_FEATS, demand, hop, ws + OFF_WT,
                                     wih, bih, bhh, ws, ws + OFF_FLOW);
  kstats <<<BS/64, 256, 0, stream>>>(ws + OFF_FLOW, ws);
  kfinal <<<1, 128, 0, stream>>>(ws, gamma, beta);
  kmlp   <<<BS/16, 256, 0, stream>>>(ws + OFF_FLOW, ws, rW1, rb1, rW2, rb2, rW3, rb3, out);
}